// Round 1
// baseline (493.836 us; speedup 1.0000x reference)
//
#include <hip/hip_runtime.h>
#include <cmath>

// Problem constants
static constexpr int EMB  = 768;
static constexpr int HS   = 64;
static constexpr int NB   = 4;
static constexpr int SEQ  = 4096;
static constexpr int MTOT = NB * SEQ;   // 16384 rows

// ---------------------------------------------------------------------------
// Projection GEMM: out = x @ W + b for Wk,Wq,Wv  (M=16384, K=768, N=64)
// 64x64 output tile per block, K-chunk 64, 256 threads, 4x4 micro-tile.
// ---------------------------------------------------------------------------
__global__ __launch_bounds__(256) void proj_kernel(
    const float* __restrict__ x,
    const float* __restrict__ Wk, const float* __restrict__ bk,
    const float* __restrict__ Wq, const float* __restrict__ bq,
    const float* __restrict__ Wv, const float* __restrict__ bv,
    float* __restrict__ kout, float* __restrict__ qout, float* __restrict__ vout)
{
    const int tid     = threadIdx.x;
    const int rowTile = blockIdx.x;   // 0..255
    const int which   = blockIdx.y;   // 0:k 1:q 2:v

    const float* W  = (which == 0) ? Wk : (which == 1) ? Wq : Wv;
    const float* bb = (which == 0) ? bk : (which == 1) ? bq : bv;
    float* out      = (which == 0) ? kout : (which == 1) ? qout : vout;

    // pad 4 -> row stride 68 floats = 272 B (16B aligned, bank rotation 4)
    __shared__ float xs[64][68];
    __shared__ float ws[64][68];   // ws[k][n]

    const int ty = tid >> 4;   // 0..15 -> rows ty*4..+3
    const int tx = tid & 15;   // 0..15 -> cols tx*4..+3
    const int row0 = rowTile * 64;

    float acc[4][4] = {};

    for (int k0 = 0; k0 < EMB; k0 += 64) {
        #pragma unroll
        for (int t = 0; t < 4; ++t) {
            const int fi = tid + t * 256;        // 0..1023
            const int r  = fi >> 4;              // 0..63
            const int c4 = (fi & 15) << 2;       // 0,4,..,60
            *(float4*)&xs[r][c4] = *(const float4*)&x[(size_t)(row0 + r) * EMB + k0 + c4];
            *(float4*)&ws[r][c4] = *(const float4*)&W[(size_t)(k0 + r) * HS + c4];
        }
        __syncthreads();

        #pragma unroll
        for (int kk = 0; kk < 64; kk += 4) {
            float4 a4[4], b4[4];
            #pragma unroll
            for (int i = 0; i < 4; ++i) a4[i] = *(const float4*)&xs[ty * 4 + i][kk];
            #pragma unroll
            for (int u = 0; u < 4; ++u) b4[u] = *(const float4*)&ws[kk + u][tx * 4];
            #pragma unroll
            for (int i = 0; i < 4; ++i) {
                const float a0 = a4[i].x, a1 = a4[i].y, a2 = a4[i].z, a3 = a4[i].w;
                acc[i][0] += a0 * b4[0].x + a1 * b4[1].x + a2 * b4[2].x + a3 * b4[3].x;
                acc[i][1] += a0 * b4[0].y + a1 * b4[1].y + a2 * b4[2].y + a3 * b4[3].y;
                acc[i][2] += a0 * b4[0].z + a1 * b4[1].z + a2 * b4[2].z + a3 * b4[3].z;
                acc[i][3] += a0 * b4[0].w + a1 * b4[1].w + a2 * b4[2].w + a3 * b4[3].w;
            }
        }
        __syncthreads();
    }

    const float4 bias = *(const float4*)&bb[tx * 4];
    #pragma unroll
    for (int i = 0; i < 4; ++i) {
        float4 r;
        r.x = acc[i][0] + bias.x;
        r.y = acc[i][1] + bias.y;
        r.z = acc[i][2] + bias.z;
        r.w = acc[i][3] + bias.w;
        *(float4*)&out[(size_t)(row0 + ty * 4 + i) * HS + tx * 4] = r;
    }
}

// ---------------------------------------------------------------------------
// Flash attention (fp32). Q-role = k-projection, K-role = q-projection.
// t-tile = 32 rows, s-tile = 64. Block handles t-tiles (pair, 127-pair)
// => exactly 65 s-iterations per block (perfect balance).
// Thread mapping: row = tid>>3 (32 rows), 8 lanes per row each owning 8 cols.
// ---------------------------------------------------------------------------
__global__ __launch_bounds__(256) void attn_kernel(
    const float* __restrict__ kbuf,   // Q role (B,T,HS)
    const float* __restrict__ qbuf,   // K role
    const float* __restrict__ vbuf,
    float* __restrict__ out)
{
    const int bz   = blockIdx.y;      // batch
    const int pair = blockIdx.x;      // 0..63
    const int tid  = threadIdx.x;

    __shared__ float qs[32][68];      // Q tile, row-major
    __shared__ float kt[64][68];      // K tile TRANSPOSED: kt[kk][s]
    __shared__ float vs[64][68];      // V tile, row-major
    __shared__ float ps[32][68];      // P tile

    const float* Qb = kbuf + (size_t)bz * SEQ * HS;
    const float* Kb = qbuf + (size_t)bz * SEQ * HS;
    const float* Vb = vbuf + (size_t)bz * SEQ * HS;
    float*       Ob = out  + (size_t)bz * SEQ * HS;

    const int row = tid >> 3;   // 0..31
    const int g   = tid & 7;    // 0..7
    const int jj0 = g * 8;      // owned column base (0..56)

    for (int half = 0; half < 2; ++half) {
        const int j  = (half == 0) ? pair : (127 - pair);
        const int r0 = j * 32;
        const int nS = (j >> 1) + 1;     // s-tiles needed (causal)

        __syncthreads();
        // load Q tile 32x64 (2 float4 per thread)
        #pragma unroll
        for (int t = 0; t < 2; ++t) {
            const int fi = tid + t * 256;       // 0..511
            const int r  = fi >> 4;
            const int c4 = (fi & 15) << 2;
            *(float4*)&qs[r][c4] = *(const float4*)&Qb[(size_t)(r0 + r) * HS + c4];
        }

        float m_r = -INFINITY, l_r = 0.0f;
        float o[8] = {};

        for (int s0i = 0; s0i < nS; ++s0i) {
            const int s0 = s0i * 64;
            __syncthreads();   // Q visible / previous PV done before overwrite
            #pragma unroll
            for (int t = 0; t < 4; ++t) {
                const int fi = tid + t * 256;   // 0..1023
                const int r  = fi >> 4;         // 0..63
                const int c4 = (fi & 15) << 2;
                const float4 kv = *(const float4*)&Kb[(size_t)(s0 + r) * HS + c4];
                kt[c4 + 0][r] = kv.x;
                kt[c4 + 1][r] = kv.y;
                kt[c4 + 2][r] = kv.z;
                kt[c4 + 3][r] = kv.w;
                *(float4*)&vs[r][c4] = *(const float4*)&Vb[(size_t)(s0 + r) * HS + c4];
            }
            __syncthreads();

            // S = q_row . k_col over 64 dims, 8 cols per thread
            float sc[8] = {};
            #pragma unroll
            for (int kk = 0; kk < 64; kk += 4) {
                const float4 a4 = *(const float4*)&qs[row][kk];
                #pragma unroll
                for (int u = 0; u < 4; ++u) {
                    const float a = (u == 0) ? a4.x : (u == 1) ? a4.y : (u == 2) ? a4.z : a4.w;
                    const float4 b0 = *(const float4*)&kt[kk + u][jj0];
                    const float4 b1 = *(const float4*)&kt[kk + u][jj0 + 4];
                    sc[0] += a * b0.x; sc[1] += a * b0.y; sc[2] += a * b0.z; sc[3] += a * b0.w;
                    sc[4] += a * b1.x; sc[5] += a * b1.y; sc[6] += a * b1.z; sc[7] += a * b1.w;
                }
            }

            // causal mask
            const int tglob = r0 + row;
            #pragma unroll
            for (int c = 0; c < 8; ++c)
                if (s0 + jj0 + c > tglob) sc[c] = -INFINITY;

            // row-wise online softmax (8 lanes per row)
            float mx = sc[0];
            #pragma unroll
            for (int c = 1; c < 8; ++c) mx = fmaxf(mx, sc[c]);
            #pragma unroll
            for (int off = 1; off < 8; off <<= 1) mx = fmaxf(mx, __shfl_xor(mx, off));

            const float m_new = fmaxf(m_r, mx);
            float p[8];
            float sum = 0.0f;
            #pragma unroll
            for (int c = 0; c < 8; ++c) { p[c] = __expf(sc[c] - m_new); sum += p[c]; }
            #pragma unroll
            for (int off = 1; off < 8; off <<= 1) sum += __shfl_xor(sum, off);

            const float alpha = __expf(m_r - m_new);   // 0 on first tile
            l_r = l_r * alpha + sum;
            m_r = m_new;

            *(float4*)&ps[row][jj0]     = make_float4(p[0], p[1], p[2], p[3]);
            *(float4*)&ps[row][jj0 + 4] = make_float4(p[4], p[5], p[6], p[7]);
            __syncthreads();

            // O = O*alpha + P @ V
            #pragma unroll
            for (int c = 0; c < 8; ++c) o[c] *= alpha;
            #pragma unroll
            for (int s = 0; s < 64; s += 4) {
                const float4 pw = *(const float4*)&ps[row][s];
                #pragma unroll
                for (int u = 0; u < 4; ++u) {
                    const float w = (u == 0) ? pw.x : (u == 1) ? pw.y : (u == 2) ? pw.z : pw.w;
                    const float4 v0 = *(const float4*)&vs[s + u][jj0];
                    const float4 v1 = *(const float4*)&vs[s + u][jj0 + 4];
                    o[0] += w * v0.x; o[1] += w * v0.y; o[2] += w * v0.z; o[3] += w * v0.w;
                    o[4] += w * v1.x; o[5] += w * v1.y; o[6] += w * v1.z; o[7] += w * v1.w;
                }
            }
        }

        // epilogue: normalize and store
        const float inv_l = 1.0f / l_r;
        float4 r0v, r1v;
        r0v.x = o[0] * inv_l; r0v.y = o[1] * inv_l; r0v.z = o[2] * inv_l; r0v.w = o[3] * inv_l;
        r1v.x = o[4] * inv_l; r1v.y = o[5] * inv_l; r1v.z = o[6] * inv_l; r1v.w = o[7] * inv_l;
        *(float4*)&Ob[(size_t)(r0 + row) * HS + jj0]     = r0v;
        *(float4*)&Ob[(size_t)(r0 + row) * HS + jj0 + 4] = r1v;
    }
}

// ---------------------------------------------------------------------------
extern "C" void kernel_launch(void* const* d_in, const int* in_sizes, int n_in,
                              void* d_out, int out_size, void* d_ws, size_t ws_size,
                              hipStream_t stream)
{
    const float* x  = (const float*)d_in[0];
    const float* Wk = (const float*)d_in[1];
    const float* bk = (const float*)d_in[2];
    const float* Wq = (const float*)d_in[3];
    const float* bq = (const float*)d_in[4];
    const float* Wv = (const float*)d_in[5];
    const float* bv = (const float*)d_in[6];
    float* out = (float*)d_out;

    float* kbuf = (float*)d_ws;                       // (B,T,HS)
    float* qbuf = kbuf + (size_t)MTOT * HS;
    float* vbuf = qbuf + (size_t)MTOT * HS;

    dim3 pgrid(MTOT / 64, 3);
    proj_kernel<<<pgrid, 256, 0, stream>>>(x, Wk, bk, Wq, bq, Wv, bv, kbuf, qbuf, vbuf);

    dim3 agrid(64, NB);
    attn_kernel<<<agrid, 256, 0, stream>>>(kbuf, qbuf, vbuf, out);
}

// Round 2
// 334.042 us; speedup vs baseline: 1.4784x; 1.4784x over previous
//
#include <hip/hip_runtime.h>
#include <cmath>

static constexpr int EMB  = 768;
static constexpr int HS   = 64;
static constexpr int NB   = 4;
static constexpr int SEQ  = 4096;
static constexpr int MTOT = NB * SEQ;   // 16384 rows

typedef __attribute__((ext_vector_type(8))) short  short8x;
typedef __attribute__((ext_vector_type(4))) float  float4x;
typedef __attribute__((ext_vector_type(4))) unsigned short ushort4x;

// round-to-nearest-even fp32 -> bf16 bits
__device__ inline unsigned short rne16(float f) {
    unsigned u = __builtin_bit_cast(unsigned, f);
    unsigned r = u + 0x7FFFu + ((u >> 16) & 1u);
    return (unsigned short)(r >> 16);
}
__device__ inline float bf2f(unsigned short h) {
    return __builtin_bit_cast(float, ((unsigned)h) << 16);
}

// ---------------------------------------------------------------------------
// Pack Wk/Wq/Wv (fp32 [768][64]) into MFMA B-fragment layout, split hi/lo bf16.
// Layout: [p(2)][kc(24)][nng(12)][lane(64)][j(8)]  (nng = which*4 + nn)
// B[k][n]: n = nn*16 + (lane&15), k = kc*32 + (lane>>4)*8 + j
// ---------------------------------------------------------------------------
__global__ __launch_bounds__(256) void convert_w(
    const float* __restrict__ Wk, const float* __restrict__ Wq, const float* __restrict__ Wv,
    unsigned short* __restrict__ wpk)
{
    const int t    = blockIdx.x * 256 + threadIdx.x;  // 0..36863
    const int lane = t & 63;
    const int rest = t >> 6;        // 0..575
    const int nng  = rest % 12;
    const int kcp  = rest / 12;     // 0..47
    const int kc   = kcp % 24;
    const int p    = kcp / 24;      // 0=hi 1=lo
    const int which= nng >> 2;
    const int nn   = nng & 3;
    const float* W = (which == 0) ? Wk : (which == 1) ? Wq : Wv;
    const int col  = nn * 16 + (lane & 15);
    const int kr   = kc * 32 + (lane >> 4) * 8;

    unsigned short o[8];
    #pragma unroll
    for (int j = 0; j < 8; ++j) {
        float w = W[(size_t)(kr + j) * HS + col];
        unsigned short h = rne16(w);
        o[j] = (p == 0) ? h : rne16(w - bf2f(h));
    }
    size_t base = ((size_t)((p * 24 + kc) * 12 + nng) * 64 + lane) * 8;
    *(short8x*)&wpk[base] = *(short8x*)o;
}

// ---------------------------------------------------------------------------
// Fused projection GEMM (MFMA, 3-pass split-bf16): 64 rows x {k,q,v}.
// 4 waves; wave w owns col-stripe [w*16, w*16+16) of each of k,q,v, all 64 rows.
// Outputs: khi/klo/qhi/qlo bf16 [16384][64]; vT bf16 [4][64][4096].
// ---------------------------------------------------------------------------
__global__ __launch_bounds__(256) void proj_kernel(
    const float* __restrict__ x,
    const unsigned short* __restrict__ wpk,
    const float* __restrict__ bk, const float* __restrict__ bq, const float* __restrict__ bv,
    unsigned short* __restrict__ khi, unsigned short* __restrict__ klo,
    unsigned short* __restrict__ qhi, unsigned short* __restrict__ qlo,
    unsigned short* __restrict__ vT)
{
    __shared__ unsigned short xh[64 * 72];
    __shared__ unsigned short xl[64 * 72];

    const int tid  = threadIdx.x;
    const int lane = tid & 63;
    const int w    = tid >> 6;       // wave 0..3
    const int l15  = lane & 15;
    const int quad = lane >> 4;
    const int row0 = blockIdx.x * 64;

    float4x acc[3][4] = {};          // [which][mi]

    for (int ch = 0; ch < 12; ++ch) {
        __syncthreads();
        // stage x-tile 64x64 fp32 -> split bf16 in LDS (stride 72)
        #pragma unroll
        for (int it = 0; it < 4; ++it) {
            const int fi = tid + it * 256;     // 0..1023
            const int r  = fi >> 4;            // 0..63
            const int c4 = (fi & 15) * 4;      // 0..60
            const float4 xv = *(const float4*)&x[(size_t)(row0 + r) * EMB + ch * 64 + c4];
            const unsigned short h0 = rne16(xv.x), h1 = rne16(xv.y),
                                 h2 = rne16(xv.z), h3 = rne16(xv.w);
            ushort4x hv = {h0, h1, h2, h3};
            ushort4x lv = {rne16(xv.x - bf2f(h0)), rne16(xv.y - bf2f(h1)),
                           rne16(xv.z - bf2f(h2)), rne16(xv.w - bf2f(h3))};
            *(ushort4x*)&xh[r * 72 + c4] = hv;
            *(ushort4x*)&xl[r * 72 + c4] = lv;
        }
        __syncthreads();

        #pragma unroll
        for (int k0 = 0; k0 < 64; k0 += 32) {
            const int kc = ch * 2 + (k0 >> 5);
            short8x ah[4], al[4];
            #pragma unroll
            for (int mi = 0; mi < 4; ++mi) {
                ah[mi] = *(const short8x*)&xh[(mi * 16 + l15) * 72 + k0 + quad * 8];
                al[mi] = *(const short8x*)&xl[(mi * 16 + l15) * 72 + k0 + quad * 8];
            }
            #pragma unroll
            for (int which = 0; which < 3; ++which) {
                const int nng = which * 4 + w;
                const short8x bh = *(const short8x*)&wpk[((size_t)((0 * 24 + kc) * 12 + nng) * 64 + lane) * 8];
                const short8x bl = *(const short8x*)&wpk[((size_t)((1 * 24 + kc) * 12 + nng) * 64 + lane) * 8];
                #pragma unroll
                for (int mi = 0; mi < 4; ++mi) {
                    acc[which][mi] = __builtin_amdgcn_mfma_f32_16x16x32_bf16(ah[mi], bh, acc[which][mi], 0, 0, 0);
                    acc[which][mi] = __builtin_amdgcn_mfma_f32_16x16x32_bf16(ah[mi], bl, acc[which][mi], 0, 0, 0);
                    acc[which][mi] = __builtin_amdgcn_mfma_f32_16x16x32_bf16(al[mi], bh, acc[which][mi], 0, 0, 0);
                }
            }
        }
    }

    // epilogue: C-layout row = quad*4+reg, col = lane&15 (+ 16*w stripe)
    const int col = w * 16 + l15;
    const float bkv = bk[col], bqv = bq[col], bvv = bv[col];
    #pragma unroll
    for (int mi = 0; mi < 4; ++mi) {
        const int rbase = row0 + mi * 16 + quad * 4;
        #pragma unroll
        for (int r = 0; r < 4; ++r) {
            const float kv = acc[0][mi][r] + bkv;
            const unsigned short hk = rne16(kv);
            khi[(size_t)(rbase + r) * 64 + col] = hk;
            klo[(size_t)(rbase + r) * 64 + col] = rne16(kv - bf2f(hk));
            const float qv = acc[1][mi][r] + bqv;
            const unsigned short hq = rne16(qv);
            qhi[(size_t)(rbase + r) * 64 + col] = hq;
            qlo[(size_t)(rbase + r) * 64 + col] = rne16(qv - bf2f(hq));
        }
        // v, stored transposed vT[b][h][s]; reg-dim = 4 consecutive s
        const int b = rbase / SEQ;
        const int s = rbase % SEQ;
        ushort4x vv = {rne16(acc[2][mi][0] + bvv), rne16(acc[2][mi][1] + bvv),
                       rne16(acc[2][mi][2] + bvv), rne16(acc[2][mi][3] + bvv)};
        *(ushort4x*)&vT[((size_t)b * 64 + col) * SEQ + s] = vv;
    }
}

// ---------------------------------------------------------------------------
// Flash attention, MFMA. Q-role = k-proj (split hi/lo), K-role = q-proj
// (split hi/lo), V single bf16 (transposed layout).
// Block: t-tile 64 rows, 4 waves, wave owns rows 16w..16w+15, all 64 s-cols.
// Softmax fully in-wave (shfl over 16-lane groups). P via LDS (C->A layout).
// ---------------------------------------------------------------------------
__global__ __launch_bounds__(256) void attn_kernel(
    const unsigned short* __restrict__ khi, const unsigned short* __restrict__ klo,
    const unsigned short* __restrict__ qhi, const unsigned short* __restrict__ qlo,
    const unsigned short* __restrict__ vT,
    float* __restrict__ out)
{
    __shared__ unsigned short kh_s[64 * 72];
    __shared__ unsigned short kl_s[64 * 72];
    __shared__ unsigned short vt_s[64 * 72];
    __shared__ unsigned short ps[64 * 72];

    const int tid  = threadIdx.x;
    const int lane = tid & 63;
    const int w    = tid >> 6;
    const int l15  = lane & 15;
    const int quad = lane >> 4;
    const int b    = blockIdx.y;
    const int j    = blockIdx.x;     // t-tile index
    const int t0   = j * 64;
    const size_t rowb = (size_t)b * SEQ;

    // Q-role A-frags (rows t0+16w+l15), k = head dim: 2 k-halves x {hi,lo}
    const int qrow = t0 + 16 * w + l15;
    short8x qa_h[2], qa_l[2];
    #pragma unroll
    for (int k0 = 0; k0 < 2; ++k0) {
        qa_h[k0] = *(const short8x*)&khi[(rowb + qrow) * 64 + k0 * 32 + quad * 8];
        qa_l[k0] = *(const short8x*)&klo[(rowb + qrow) * 64 + k0 * 32 + quad * 8];
    }

    float m_r[4] = {-1e30f, -1e30f, -1e30f, -1e30f};
    float l_r[4] = {0.f, 0.f, 0.f, 0.f};
    float4x oacc[4] = {};            // [nn]

    const int nS = j + 1;
    const int sr = tid >> 3;         // 0..31 staging row
    const int c8 = (tid & 7) * 8;    // staging col (bf16 units)

    for (int ci = 0; ci < nS; ++ci) {
        const int s0 = ci * 64;
        __syncthreads();
        // stage K-role (hi/lo) rows [s][h] and V transposed [h][s]
        #pragma unroll
        for (int it = 0; it < 2; ++it) {
            const int r = sr + it * 32;
            *(short8x*)&kh_s[r * 72 + c8] = *(const short8x*)&qhi[(rowb + s0 + r) * 64 + c8];
            *(short8x*)&kl_s[r * 72 + c8] = *(const short8x*)&qlo[(rowb + s0 + r) * 64 + c8];
            *(short8x*)&vt_s[r * 72 + c8] = *(const short8x*)&vT[((size_t)b * 64 + r) * SEQ + s0 + c8];
        }
        __syncthreads();

        // S = Qrole . KroleT, 3-pass split, 4 n-subtiles
        float4x sacc[4] = {};
        #pragma unroll
        for (int k0 = 0; k0 < 2; ++k0) {
            #pragma unroll
            for (int nn = 0; nn < 4; ++nn) {
                const short8x bh = *(const short8x*)&kh_s[(nn * 16 + l15) * 72 + k0 * 32 + quad * 8];
                const short8x bl = *(const short8x*)&kl_s[(nn * 16 + l15) * 72 + k0 * 32 + quad * 8];
                sacc[nn] = __builtin_amdgcn_mfma_f32_16x16x32_bf16(qa_h[k0], bh, sacc[nn], 0, 0, 0);
                sacc[nn] = __builtin_amdgcn_mfma_f32_16x16x32_bf16(qa_h[k0], bl, sacc[nn], 0, 0, 0);
                sacc[nn] = __builtin_amdgcn_mfma_f32_16x16x32_bf16(qa_l[k0], bh, sacc[nn], 0, 0, 0);
            }
        }

        // mask + online softmax, per C-row (quad*4+r)
        const int trow = t0 + 16 * w + quad * 4;
        float alpha[4];
        #pragma unroll
        for (int r = 0; r < 4; ++r) {
            float mx = -3e38f;
            #pragma unroll
            for (int nn = 0; nn < 4; ++nn) {
                float v = sacc[nn][r];
                const int colg = s0 + nn * 16 + l15;
                if (colg > trow + r) v = -3e38f;   // causal (no-op off-diagonal)
                sacc[nn][r] = v;
                mx = fmaxf(mx, v);
            }
            mx = fmaxf(mx, __shfl_xor(mx, 1));
            mx = fmaxf(mx, __shfl_xor(mx, 2));
            mx = fmaxf(mx, __shfl_xor(mx, 4));
            mx = fmaxf(mx, __shfl_xor(mx, 8));
            const float mn = fmaxf(m_r[r], mx);
            alpha[r] = __expf(m_r[r] - mn);
            float sum = 0.f;
            #pragma unroll
            for (int nn = 0; nn < 4; ++nn) {
                const float e = __expf(sacc[nn][r] - mn);
                const unsigned short h = rne16(e);     // P in bf16
                sum += bf2f(h);                        // l consistent with bf16 P
                ps[(16 * w + quad * 4 + r) * 72 + nn * 16 + l15] = h;
            }
            sum += __shfl_xor(sum, 1);
            sum += __shfl_xor(sum, 2);
            sum += __shfl_xor(sum, 4);
            sum += __shfl_xor(sum, 8);
            l_r[r] = l_r[r] * alpha[r] + sum;
            m_r[r] = mn;
        }
        __syncthreads();   // ps visible to PV reads

        // O = O*alpha + P @ V
        #pragma unroll
        for (int nn = 0; nn < 4; ++nn)
            #pragma unroll
            for (int r = 0; r < 4; ++r) oacc[nn][r] *= alpha[r];
        #pragma unroll
        for (int k0 = 0; k0 < 2; ++k0) {
            const short8x pa = *(const short8x*)&ps[(16 * w + l15) * 72 + k0 * 32 + quad * 8];
            #pragma unroll
            for (int nn = 0; nn < 4; ++nn) {
                const short8x vb = *(const short8x*)&vt_s[(nn * 16 + l15) * 72 + k0 * 32 + quad * 8];
                oacc[nn] = __builtin_amdgcn_mfma_f32_16x16x32_bf16(pa, vb, oacc[nn], 0, 0, 0);
            }
        }
    }

    // epilogue
    float inv[4];
    #pragma unroll
    for (int r = 0; r < 4; ++r) inv[r] = 1.0f / l_r[r];
    #pragma unroll
    for (int nn = 0; nn < 4; ++nn)
        #pragma unroll
        for (int r = 0; r < 4; ++r)
            out[(rowb + t0 + 16 * w + quad * 4 + r) * 64 + nn * 16 + l15] = oacc[nn][r] * inv[r];
}

// ---------------------------------------------------------------------------
extern "C" void kernel_launch(void* const* d_in, const int* in_sizes, int n_in,
                              void* d_out, int out_size, void* d_ws, size_t ws_size,
                              hipStream_t stream)
{
    const float* x  = (const float*)d_in[0];
    const float* Wk = (const float*)d_in[1];
    const float* bk = (const float*)d_in[2];
    const float* Wq = (const float*)d_in[3];
    const float* bq = (const float*)d_in[4];
    const float* Wv = (const float*)d_in[5];
    const float* bv = (const float*)d_in[6];
    float* out = (float*)d_out;

    const size_t NE = (size_t)MTOT * HS;      // 1M elements
    unsigned short* khi = (unsigned short*)d_ws;
    unsigned short* klo = khi + NE;
    unsigned short* qhi = klo + NE;
    unsigned short* qlo = qhi + NE;
    unsigned short* vT  = qlo + NE;
    unsigned short* wpk = vT + NE;            // 2*24*12*64*8 = 294912 shorts

    convert_w<<<144, 256, 0, stream>>>(Wk, Wq, Wv, wpk);
    proj_kernel<<<MTOT / 64, 256, 0, stream>>>(x, wpk, bk, bq, bv, khi, klo, qhi, qlo, vT);
    dim3 agrid(64, NB);
    attn_kernel<<<agrid, 256, 0, stream>>>(khi, klo, qhi, qlo, vT, out);
}

// Round 3
// 169.820 us; speedup vs baseline: 2.9080x; 1.9670x over previous
//
#include <hip/hip_runtime.h>
#include <cmath>

static constexpr int EMB  = 768;
static constexpr int HS   = 64;
static constexpr int NB   = 4;
static constexpr int SEQ  = 4096;
static constexpr int MTOT = NB * SEQ;   // 16384 rows

typedef __attribute__((ext_vector_type(8))) short  short8x;
typedef __attribute__((ext_vector_type(4))) float  float4x;
typedef __attribute__((ext_vector_type(4))) unsigned short ushort4x;

// round-to-nearest-even fp32 -> bf16 bits
__device__ inline unsigned short rne16(float f) {
    unsigned u = __builtin_bit_cast(unsigned, f);
    unsigned r = u + 0x7FFFu + ((u >> 16) & 1u);
    return (unsigned short)(r >> 16);
}
__device__ inline float bf2f(unsigned short h) {
    return __builtin_bit_cast(float, ((unsigned)h) << 16);
}

// ---------------------------------------------------------------------------
// Pack Wk/Wq/Wv (fp32 [768][64]) into MFMA B-fragment layout, split hi/lo bf16.
// Layout: [p(2)][kc(24)][nng(12)][lane(64)][j(8)]  (nng = which*4 + nn)
// B[k][n]: n = nn*16 + (lane&15), k = kc*32 + (lane>>4)*8 + j
// ---------------------------------------------------------------------------
__global__ __launch_bounds__(256) void convert_w(
    const float* __restrict__ Wk, const float* __restrict__ Wq, const float* __restrict__ Wv,
    unsigned short* __restrict__ wpk)
{
    const int t    = blockIdx.x * 256 + threadIdx.x;  // 0..36863
    const int lane = t & 63;
    const int rest = t >> 6;        // 0..575
    const int nng  = rest % 12;
    const int kcp  = rest / 12;     // 0..47
    const int kc   = kcp % 24;
    const int p    = kcp / 24;      // 0=hi 1=lo
    const int which= nng >> 2;
    const int nn   = nng & 3;
    const float* W = (which == 0) ? Wk : (which == 1) ? Wq : Wv;
    const int col  = nn * 16 + (lane & 15);
    const int kr   = kc * 32 + (lane >> 4) * 8;

    unsigned short o[8];
    #pragma unroll
    for (int j = 0; j < 8; ++j) {
        float w = W[(size_t)(kr + j) * HS + col];
        unsigned short h = rne16(w);
        o[j] = (p == 0) ? h : rne16(w - bf2f(h));
    }
    size_t base = ((size_t)((p * 24 + kc) * 12 + nng) * 64 + lane) * 8;
    *(short8x*)&wpk[base] = *(short8x*)o;
}

// ---------------------------------------------------------------------------
// Projection GEMM v2: 32-row tiles (512 blocks -> 2 blocks/CU, 8 waves/CU),
// double-buffered x staging. Wave w owns col-stripe nn=w of each of k,q,v,
// 2 row-groups (mi). 3-pass split-bf16 MFMA.
// ---------------------------------------------------------------------------
__global__ __launch_bounds__(256) void proj_kernel(
    const float* __restrict__ x,
    const unsigned short* __restrict__ wpk,
    const float* __restrict__ bk, const float* __restrict__ bq, const float* __restrict__ bv,
    unsigned short* __restrict__ khi, unsigned short* __restrict__ klo,
    unsigned short* __restrict__ qhi, unsigned short* __restrict__ qlo,
    unsigned short* __restrict__ vT)
{
    __shared__ unsigned short xh[2][32 * 72];
    __shared__ unsigned short xl[2][32 * 72];

    const int tid  = threadIdx.x;
    const int lane = tid & 63;
    const int w    = tid >> 6;       // wave 0..3 -> nn stripe
    const int l15  = lane & 15;
    const int quad = lane >> 4;
    const int row0 = blockIdx.x * 32;

    float4x acc[3][2] = {};          // [which][mi]
    float4  pre[2];

    const int s_r  = tid >> 4;           // 0..31 staging row
    const int s_c4 = (tid & 15) * 4;     // staging col base

    // prefetch chunk 0
    #pragma unroll
    for (int it = 0; it < 2; ++it) {
        const int fi = tid + it * 256;
        const int r  = fi >> 4, c4 = (fi & 15) * 4;
        pre[it] = *(const float4*)&x[(size_t)(row0 + r) * EMB + 0 * 64 + c4];
    }
    #pragma unroll
    for (int it = 0; it < 2; ++it) {
        const int fi = tid + it * 256;
        const int r  = fi >> 4, c4 = (fi & 15) * 4;
        const float4 xv = pre[it];
        const unsigned short h0 = rne16(xv.x), h1 = rne16(xv.y),
                             h2 = rne16(xv.z), h3 = rne16(xv.w);
        ushort4x hv = {h0, h1, h2, h3};
        ushort4x lv = {rne16(xv.x - bf2f(h0)), rne16(xv.y - bf2f(h1)),
                       rne16(xv.z - bf2f(h2)), rne16(xv.w - bf2f(h3))};
        *(ushort4x*)&xh[0][r * 72 + c4] = hv;
        *(ushort4x*)&xl[0][r * 72 + c4] = lv;
    }

    for (int ch = 0; ch < 12; ++ch) {
        // issue next chunk's global loads (hidden behind this chunk's compute)
        if (ch + 1 < 12) {
            #pragma unroll
            for (int it = 0; it < 2; ++it) {
                const int fi = tid + it * 256;
                const int r  = fi >> 4, c4 = (fi & 15) * 4;
                pre[it] = *(const float4*)&x[(size_t)(row0 + r) * EMB + (ch + 1) * 64 + c4];
            }
        }
        __syncthreads();
        const int buf = ch & 1;

        #pragma unroll
        for (int k0i = 0; k0i < 2; ++k0i) {
            const int k0 = k0i * 32;
            const int kc = ch * 2 + k0i;
            short8x ah[2], al[2];
            #pragma unroll
            for (int mi = 0; mi < 2; ++mi) {
                ah[mi] = *(const short8x*)&xh[buf][(mi * 16 + l15) * 72 + k0 + quad * 8];
                al[mi] = *(const short8x*)&xl[buf][(mi * 16 + l15) * 72 + k0 + quad * 8];
            }
            #pragma unroll
            for (int which = 0; which < 3; ++which) {
                const int nng = which * 4 + w;
                const short8x bh = *(const short8x*)&wpk[((size_t)((0 * 24 + kc) * 12 + nng) * 64 + lane) * 8];
                const short8x bl = *(const short8x*)&wpk[((size_t)((1 * 24 + kc) * 12 + nng) * 64 + lane) * 8];
                #pragma unroll
                for (int mi = 0; mi < 2; ++mi) {
                    acc[which][mi] = __builtin_amdgcn_mfma_f32_16x16x32_bf16(ah[mi], bh, acc[which][mi], 0, 0, 0);
                    acc[which][mi] = __builtin_amdgcn_mfma_f32_16x16x32_bf16(ah[mi], bl, acc[which][mi], 0, 0, 0);
                    acc[which][mi] = __builtin_amdgcn_mfma_f32_16x16x32_bf16(al[mi], bh, acc[which][mi], 0, 0, 0);
                }
            }
        }

        if (ch + 1 < 12) {
            const int nbuf = (ch + 1) & 1;
            #pragma unroll
            for (int it = 0; it < 2; ++it) {
                const int fi = tid + it * 256;
                const int r  = fi >> 4, c4 = (fi & 15) * 4;
                const float4 xv = pre[it];
                const unsigned short h0 = rne16(xv.x), h1 = rne16(xv.y),
                                     h2 = rne16(xv.z), h3 = rne16(xv.w);
                ushort4x hv = {h0, h1, h2, h3};
                ushort4x lv = {rne16(xv.x - bf2f(h0)), rne16(xv.y - bf2f(h1)),
                               rne16(xv.z - bf2f(h2)), rne16(xv.w - bf2f(h3))};
                *(ushort4x*)&xh[nbuf][r * 72 + c4] = hv;
                *(ushort4x*)&xl[nbuf][r * 72 + c4] = lv;
            }
        }
    }

    // epilogue: C-row = quad*4+reg, col = l15 (+16*w stripe)
    const int col = w * 16 + l15;
    const float bkv = bk[col], bqv = bq[col], bvv = bv[col];
    #pragma unroll
    for (int mi = 0; mi < 2; ++mi) {
        const int rbase = row0 + mi * 16 + quad * 4;
        #pragma unroll
        for (int r = 0; r < 4; ++r) {
            const float kv = acc[0][mi][r] + bkv;
            const unsigned short hk = rne16(kv);
            khi[(size_t)(rbase + r) * 64 + col] = hk;
            klo[(size_t)(rbase + r) * 64 + col] = rne16(kv - bf2f(hk));
            const float qv = acc[1][mi][r] + bqv;
            const unsigned short hq = rne16(qv);
            qhi[(size_t)(rbase + r) * 64 + col] = hq;
            qlo[(size_t)(rbase + r) * 64 + col] = rne16(qv - bf2f(hq));
        }
        const int b = rbase / SEQ;
        const int s = rbase % SEQ;
        ushort4x vv = {rne16(acc[2][mi][0] + bvv), rne16(acc[2][mi][1] + bvv),
                       rne16(acc[2][mi][2] + bvv), rne16(acc[2][mi][3] + bvv)};
        *(ushort4x*)&vT[((size_t)b * 64 + col) * SEQ + s] = vv;
    }
}

// ---------------------------------------------------------------------------
// Flash attention v3: static-max softmax (no running max -> associative),
// split-s across SPLITS blocks per (b, j). Partial (O, l) to workspace.
// Block n -> j = slowest (interleaves heavy/light blocks across CUs).
// ---------------------------------------------------------------------------
__global__ __launch_bounds__(256) void attn_kernel(
    const unsigned short* __restrict__ khi, const unsigned short* __restrict__ klo,
    const unsigned short* __restrict__ qhi, const unsigned short* __restrict__ qlo,
    const unsigned short* __restrict__ vT,
    float* __restrict__ Opart, float* __restrict__ lpart, int SPLITS)
{
    __shared__ unsigned short kh_s[64 * 72];
    __shared__ unsigned short kl_s[64 * 72];
    __shared__ unsigned short vt_s[64 * 72];
    __shared__ unsigned short ps[64 * 72];

    const int tid  = threadIdx.x;
    const int lane = tid & 63;
    const int w    = tid >> 6;
    const int l15  = lane & 15;
    const int quad = lane >> 4;

    const int n    = blockIdx.x;
    const int sp   = n % SPLITS;
    const int rest = n / SPLITS;
    const int b    = rest % NB;
    const int j    = rest / NB;      // t-tile
    const int t0   = j * 64;
    const size_t rowb = (size_t)b * SEQ;

    // Q-role A-frags (rows t0+16w+l15): 2 k-halves x {hi,lo}
    const int qrow = t0 + 16 * w + l15;
    short8x qa_h[2], qa_l[2];
    #pragma unroll
    for (int k0 = 0; k0 < 2; ++k0) {
        qa_h[k0] = *(const short8x*)&khi[(rowb + qrow) * 64 + k0 * 32 + quad * 8];
        qa_l[k0] = *(const short8x*)&klo[(rowb + qrow) * 64 + k0 * 32 + quad * 8];
    }

    float l_r[4] = {0.f, 0.f, 0.f, 0.f};
    float4x oacc[4] = {};            // [nn]

    const int sr = tid >> 3;         // staging row 0..31
    const int c8 = (tid & 7) * 8;    // staging col (bf16 units)

    for (int ci = sp; ci <= j; ci += SPLITS) {
        const int s0 = ci * 64;
        __syncthreads();
        #pragma unroll
        for (int it = 0; it < 2; ++it) {
            const int r = sr + it * 32;
            *(short8x*)&kh_s[r * 72 + c8] = *(const short8x*)&qhi[(rowb + s0 + r) * 64 + c8];
            *(short8x*)&kl_s[r * 72 + c8] = *(const short8x*)&qlo[(rowb + s0 + r) * 64 + c8];
            *(short8x*)&vt_s[r * 72 + c8] = *(const short8x*)&vT[((size_t)b * 64 + r) * SEQ + s0 + c8];
        }
        __syncthreads();

        // S = Qrole . KroleT (3-pass split, 4 n-subtiles)
        float4x sacc[4] = {};
        #pragma unroll
        for (int k0 = 0; k0 < 2; ++k0) {
            #pragma unroll
            for (int nn = 0; nn < 4; ++nn) {
                const short8x bh = *(const short8x*)&kh_s[(nn * 16 + l15) * 72 + k0 * 32 + quad * 8];
                const short8x bl = *(const short8x*)&kl_s[(nn * 16 + l15) * 72 + k0 * 32 + quad * 8];
                sacc[nn] = __builtin_amdgcn_mfma_f32_16x16x32_bf16(qa_h[k0], bh, sacc[nn], 0, 0, 0);
                sacc[nn] = __builtin_amdgcn_mfma_f32_16x16x32_bf16(qa_h[k0], bl, sacc[nn], 0, 0, 0);
                sacc[nn] = __builtin_amdgcn_mfma_f32_16x16x32_bf16(qa_l[k0], bh, sacc[nn], 0, 0, 0);
            }
        }

        // causal mask only on the diagonal tile (wave-uniform branch)
        if (ci == j) {
            const int trow = t0 + 16 * w + quad * 4;
            #pragma unroll
            for (int nn = 0; nn < 4; ++nn) {
                const int colg = s0 + nn * 16 + l15;
                #pragma unroll
                for (int r = 0; r < 4; ++r)
                    if (colg > trow + r) sacc[nn][r] = -1e30f;
            }
        }

        // p = exp(S) (static max; clamp is overflow insurance), accumulate l
        #pragma unroll
        for (int nn = 0; nn < 4; ++nn) {
            #pragma unroll
            for (int r = 0; r < 4; ++r) {
                const float e = __expf(fminf(sacc[nn][r], 80.0f));
                const unsigned short h = rne16(e);
                l_r[r] += bf2f(h);                 // l consistent with bf16 P
                ps[(16 * w + quad * 4 + r) * 72 + nn * 16 + l15] = h;
            }
        }
        __syncthreads();

        // O += P @ V  (no rescale needed)
        #pragma unroll
        for (int k0 = 0; k0 < 2; ++k0) {
            const short8x pa = *(const short8x*)&ps[(16 * w + l15) * 72 + k0 * 32 + quad * 8];
            #pragma unroll
            for (int nn = 0; nn < 4; ++nn) {
                const short8x vb = *(const short8x*)&vt_s[(nn * 16 + l15) * 72 + k0 * 32 + quad * 8];
                oacc[nn] = __builtin_amdgcn_mfma_f32_16x16x32_bf16(pa, vb, oacc[nn], 0, 0, 0);
            }
        }
    }

    // epilogue: reduce l over 16 lanes, store partials
    #pragma unroll
    for (int r = 0; r < 4; ++r) {
        l_r[r] += __shfl_xor(l_r[r], 1);
        l_r[r] += __shfl_xor(l_r[r], 2);
        l_r[r] += __shfl_xor(l_r[r], 4);
        l_r[r] += __shfl_xor(l_r[r], 8);
    }
    const size_t part = (size_t)(j * NB + b) * SPLITS + sp;
    float* Op = Opart + part * 4096;
    #pragma unroll
    for (int nn = 0; nn < 4; ++nn)
        #pragma unroll
        for (int r = 0; r < 4; ++r)
            Op[(16 * w + quad * 4 + r) * 64 + nn * 16 + l15] = oacc[nn][r];
    if (l15 == 0) {
        #pragma unroll
        for (int r = 0; r < 4; ++r)
            lpart[part * 64 + 16 * w + quad * 4 + r] = l_r[r];
    }
}

// ---------------------------------------------------------------------------
// Combine: out = (sum_sp O_p) / (sum_sp l_p)
// ---------------------------------------------------------------------------
__global__ __launch_bounds__(256) void combine_kernel(
    const float* __restrict__ Opart, const float* __restrict__ lpart,
    float* __restrict__ out, int SPLITS)
{
    const int j   = blockIdx.x;
    const int b   = blockIdx.y;
    const int tid = threadIdx.x;
    const int row = tid >> 2;            // 0..63
    const int c0  = (tid & 3) * 16;
    const size_t base = (size_t)(j * NB + b) * SPLITS;

    float4 acc[4] = {};
    float l = 0.f;
    for (int sp = 0; sp < SPLITS; ++sp) {
        const float* Op = Opart + (base + sp) * 4096;
        #pragma unroll
        for (int u = 0; u < 4; ++u) {
            const float4 v = *(const float4*)&Op[row * 64 + c0 + u * 4];
            acc[u].x += v.x; acc[u].y += v.y; acc[u].z += v.z; acc[u].w += v.w;
        }
        l += lpart[(base + sp) * 64 + row];
    }
    const float inv = 1.0f / l;
    float* o = out + ((size_t)b * SEQ + j * 64 + row) * 64 + c0;
    #pragma unroll
    for (int u = 0; u < 4; ++u) {
        float4 v;
        v.x = acc[u].x * inv; v.y = acc[u].y * inv;
        v.z = acc[u].z * inv; v.w = acc[u].w * inv;
        *(float4*)&o[u * 4] = v;
    }
}

// ---------------------------------------------------------------------------
extern "C" void kernel_launch(void* const* d_in, const int* in_sizes, int n_in,
                              void* d_out, int out_size, void* d_ws, size_t ws_size,
                              hipStream_t stream)
{
    const float* x  = (const float*)d_in[0];
    const float* Wk = (const float*)d_in[1];
    const float* bk = (const float*)d_in[2];
    const float* Wq = (const float*)d_in[3];
    const float* bq = (const float*)d_in[4];
    const float* Wv = (const float*)d_in[5];
    const float* bv = (const float*)d_in[6];
    float* out = (float*)d_out;

    const size_t NE = (size_t)MTOT * HS;      // 1M elements
    unsigned short* khi = (unsigned short*)d_ws;
    unsigned short* klo = khi + NE;
    unsigned short* qhi = klo + NE;
    unsigned short* qlo = qhi + NE;
    unsigned short* vT  = qlo + NE;
    unsigned short* wpk = vT + NE;            // 294912 shorts
    const size_t fixed_bytes = 5 * NE * sizeof(unsigned short) + 294912 * sizeof(unsigned short);

    // pick the largest split count whose partials fit the workspace
    int SPLITS = 4;
    while (SPLITS > 1) {
        const size_t need = fixed_bytes +
            (size_t)NB * 64 * SPLITS * (64 * 64 + 64) * sizeof(float);
        if (need <= ws_size) break;
        SPLITS >>= 1;
    }
    float* Opart = (float*)((char*)d_ws + fixed_bytes);
    float* lpart = Opart + (size_t)NB * 64 * SPLITS * 64 * 64;

    convert_w<<<144, 256, 0, stream>>>(Wk, Wq, Wv, wpk);
    proj_kernel<<<MTOT / 32, 256, 0, stream>>>(x, wpk, bk, bq, bv, khi, klo, qhi, qlo, vT);
    attn_kernel<<<64 * NB * SPLITS, 256, 0, stream>>>(khi, klo, qhi, qlo, vT, Opart, lpart, SPLITS);
    dim3 cgrid(64, NB);
    combine_kernel<<<cgrid, 256, 0, stream>>>(Opart, lpart, out, SPLITS);
}